// Round 1
// baseline (18399.362 us; speedup 1.0000x reference)
//
#include <hip/hip_runtime.h>
#include <hip/hip_bf16.h>
#include <math.h>

#define B_   4
#define T_   2048
#define D_   1024
#define QH   16
#define KVH  4
#define HD_  64
#define GRP  4
#define R_   (B_*T_)      // 8192 rows
#define DFF  2048
#define KVW  (KVH*2*HD_)  // 512

// ---------------- LayerNorm: one block (256 thr) per row of 1024 ----------------
__global__ __launch_bounds__(256) void ln_kernel(const float* __restrict__ x,
                                                 const float* __restrict__ g,
                                                 const float* __restrict__ bta,
                                                 float* __restrict__ out) {
    int row = blockIdx.x;
    int tid = threadIdx.x;
    const float* xr = x + (size_t)row * D_;
    int c = tid * 4;
    float4 v = *(const float4*)&xr[c];
    float s = v.x + v.y + v.z + v.w;
#pragma unroll
    for (int off = 32; off >= 1; off >>= 1) s += __shfl_xor(s, off);
    __shared__ float sm[4], sv[4];
    int wid = tid >> 6, lane = tid & 63;
    if (lane == 0) sm[wid] = s;
    __syncthreads();
    float mean = (sm[0] + sm[1] + sm[2] + sm[3]) * (1.0f / D_);
    float d0 = v.x - mean, d1 = v.y - mean, d2 = v.z - mean, d3 = v.w - mean;
    float qq = d0*d0 + d1*d1 + d2*d2 + d3*d3;
#pragma unroll
    for (int off = 32; off >= 1; off >>= 1) qq += __shfl_xor(qq, off);
    if (lane == 0) sv[wid] = qq;
    __syncthreads();
    float var = (sv[0] + sv[1] + sv[2] + sv[3]) * (1.0f / D_);
    float rstd = rsqrtf(var + 1e-5f);
    float4 gg = *(const float4*)&g[c];
    float4 bb = *(const float4*)&bta[c];
    float4 o;
    o.x = d0 * rstd * gg.x + bb.x;
    o.y = d1 * rstd * gg.y + bb.y;
    o.z = d2 * rstd * gg.z + bb.z;
    o.w = d3 * rstd * gg.w + bb.w;
    *(float4*)&(out + (size_t)row * D_)[c] = o;
}

// ---------------- Generic f32 GEMM: C = res + act(A(MxK) * W(NxK)^T + bias) ----------------
// 64x64 tile, BK=16, 256 threads, 4x4 per thread.
__global__ __launch_bounds__(256) void gemm_bt(const float* __restrict__ A,
                                               const float* __restrict__ W,
                                               const float* __restrict__ bias,
                                               const float* __restrict__ res,
                                               float* __restrict__ C,
                                               int M, int N, int K, int do_gelu) {
    __shared__ float As[64][17];
    __shared__ float Ws[64][17];
    int bm = blockIdx.y * 64, bn = blockIdx.x * 64;
    int tid = threadIdx.x;
    int lr = tid >> 2;          // 0..63 (tile row)
    int lk = (tid & 3) * 4;     // 0,4,8,12 (k offset)
    int ty = tid >> 4, tx = tid & 15;
    float acc[4][4] = {{0.f}};
    for (int k0 = 0; k0 < K; k0 += 16) {
        float4 av = *(const float4*)&A[(size_t)(bm + lr) * K + k0 + lk];
        float4 wv = *(const float4*)&W[(size_t)(bn + lr) * K + k0 + lk];
        As[lr][lk+0] = av.x; As[lr][lk+1] = av.y; As[lr][lk+2] = av.z; As[lr][lk+3] = av.w;
        Ws[lr][lk+0] = wv.x; Ws[lr][lk+1] = wv.y; Ws[lr][lk+2] = wv.z; Ws[lr][lk+3] = wv.w;
        __syncthreads();
#pragma unroll
        for (int kk = 0; kk < 16; ++kk) {
            float a[4], w[4];
#pragma unroll
            for (int i = 0; i < 4; ++i) a[i] = As[ty*4 + i][kk];
#pragma unroll
            for (int j = 0; j < 4; ++j) w[j] = Ws[tx*4 + j][kk];
#pragma unroll
            for (int i = 0; i < 4; ++i)
#pragma unroll
                for (int j = 0; j < 4; ++j) acc[i][j] = fmaf(a[i], w[j], acc[i][j]);
        }
        __syncthreads();
    }
#pragma unroll
    for (int i = 0; i < 4; ++i) {
        int row = bm + ty*4 + i;
#pragma unroll
        for (int j = 0; j < 4; ++j) {
            int col = bn + tx*4 + j;
            float val = acc[i][j];
            if (bias) val += bias[col];
            if (do_gelu) val = 0.5f * val * (1.0f + erff(val * 0.70710678118654752f));
            if (res) val += res[(size_t)row * N + col];
            C[(size_t)row * N + col] = val;
        }
    }
}

// ---------------- RoPE in-place on q (16 heads) and k-halves of kv (4 heads) ----------------
__global__ __launch_bounds__(256) void rope_kernel(float* __restrict__ q,
                                                   float* __restrict__ kv,
                                                   const float* __restrict__ cosb,
                                                   const float* __restrict__ sinb) {
    int idx = blockIdx.x * 256 + threadIdx.x;
    const int total = R_ * (QH + KVH) * (HD_/2);
    if (idx >= total) return;
    int d2   = idx & 31;
    int tmp  = idx >> 5;
    int head = tmp % (QH + KVH);
    int row  = tmp / (QH + KVH);
    int t    = row & (T_ - 1);
    float c0 = cosb[t*HD_ + 2*d2];
    float s0 = sinb[t*HD_ + 2*d2];
    float c1 = cosb[t*HD_ + 2*d2 + 1];
    float s1 = sinb[t*HD_ + 2*d2 + 1];
    float* p;
    if (head < QH) p = q  + (size_t)row * D_  + head * HD_;
    else           p = kv + (size_t)row * KVW + (head - QH) * (2*HD_);  // k part
    float x0 = p[2*d2], x1 = p[2*d2 + 1];
    p[2*d2]     = x0 * c0 - x1 * s0;
    p[2*d2 + 1] = x1 * c1 + x0 * s1;
}

// ---------------- Attention: 1 wave per q-row, online softmax over all T keys ----------------
__global__ __launch_bounds__(256) void attn_kernel(const float* __restrict__ q,
                                                   const float* __restrict__ kv,
                                                   float* __restrict__ o) {
    int wid = threadIdx.x >> 6, lane = threadIdx.x & 63;
    int b = blockIdx.x / QH, h = blockIdx.x % QH;
    int t = blockIdx.y * 4 + wid;
    int kvh = h >> 2;   // GROUP=4
    float qv = q[(size_t)(b*T_ + t) * D_ + h*HD_ + lane] * 0.125f;  // scale = HD^-0.5
    const float* kvbase = kv + (size_t)b * T_ * KVW + kvh * (2*HD_) + lane;
    float m = -1e30f, l = 0.0f, acc = 0.0f;
    for (int s = 0; s < T_; ++s) {
        const float* krow = kvbase + (size_t)s * KVW;
        float kx = krow[0];
        float vx = krow[HD_];
        float p = qv * kx;
#pragma unroll
        for (int off = 32; off >= 1; off >>= 1) p += __shfl_xor(p, off);
        float mn = fmaxf(m, p);
        float cr = __expf(m - mn);
        float pe = __expf(p - mn);
        l   = l * cr + pe;
        acc = acc * cr + pe * vx;
        m = mn;
    }
    o[(size_t)(b*T_ + t) * D_ + h*HD_ + lane] = acc / l;
}

extern "C" void kernel_launch(void* const* d_in, const int* in_sizes, int n_in,
                              void* d_out, int out_size, void* d_ws, size_t ws_size,
                              hipStream_t stream) {
    const float* x    = (const float*)d_in[0];
    const float* cosb = (const float*)d_in[1];
    const float* sinb = (const float*)d_in[2];
    const float* Wq   = (const float*)d_in[3];
    const float* Wkv  = (const float*)d_in[4];
    const float* Wo   = (const float*)d_in[5];
    const float* ln1g = (const float*)d_in[6];
    const float* ln1b = (const float*)d_in[7];
    const float* ln2g = (const float*)d_in[8];
    const float* ln2b = (const float*)d_in[9];
    const float* W1   = (const float*)d_in[10];
    const float* b1   = (const float*)d_in[11];
    const float* W2   = (const float*)d_in[12];
    const float* b2   = (const float*)d_in[13];
    float* out = (float*)d_out;

    float* ws  = (float*)d_ws;
    float* h   = ws;                            // R_*D_         (reused as h2)
    float* q   = h   + (size_t)R_ * D_;         // R_*D_         (reused for gelu buf)
    float* kvb = q   + (size_t)R_ * D_;         // R_*KVW
    float* o   = kvb + (size_t)R_ * KVW;        // R_*D_
    float* x2  = o   + (size_t)R_ * D_;         // R_*D_
    float* h2  = h;
    float* gbuf = q;                            // R_*DFF, overlaps q+kv+o (dead by then)

    // 1. LN1
    ln_kernel<<<R_, 256, 0, stream>>>(x, ln1g, ln1b, h);
    // 2. q = h @ Wq^T ; kv = h @ Wkv^T
    gemm_bt<<<dim3(D_/64,  R_/64), 256, 0, stream>>>(h, Wq,  nullptr, nullptr, q,   R_, D_,  D_, 0);
    gemm_bt<<<dim3(KVW/64, R_/64), 256, 0, stream>>>(h, Wkv, nullptr, nullptr, kvb, R_, KVW, D_, 0);
    // 3. RoPE on q and k
    {
        int total = R_ * (QH + KVH) * (HD_/2);
        rope_kernel<<<(total + 255)/256, 256, 0, stream>>>(q, kvb, cosb, sinb);
    }
    // 4. attention -> o
    attn_kernel<<<dim3(B_*QH, T_/4), 256, 0, stream>>>(q, kvb, o);
    // 5. x2 = x + o @ Wo^T
    gemm_bt<<<dim3(D_/64, R_/64), 256, 0, stream>>>(o, Wo, nullptr, x, x2, R_, D_, D_, 0);
    // 6. LN2
    ln_kernel<<<R_, 256, 0, stream>>>(x2, ln2g, ln2b, h2);
    // 7. g = gelu(h2 @ W1^T + b1)
    gemm_bt<<<dim3(DFF/64, R_/64), 256, 0, stream>>>(h2, W1, b1, nullptr, gbuf, R_, DFF, D_, 1);
    // 8. out = x2 + g @ W2^T + b2
    gemm_bt<<<dim3(D_/64, R_/64), 256, 0, stream>>>(gbuf, W2, b2, x2, out, R_, D_, DFF, 0);
}

// Round 4
// 2483.219 us; speedup vs baseline: 7.4095x; 7.4095x over previous
//
#include <hip/hip_runtime.h>
#include <hip/hip_bf16.h>
#include <math.h>

#define B_   4
#define T_   2048
#define D_   1024
#define QH   16
#define KVH  4
#define HD_  64
#define GRP  4
#define R_   (B_*T_)      // 8192 rows
#define DFF  2048
#define KVW  (KVH*2*HD_)  // 512
#define LDK  72           // padded LDS row stride (elements): 144B -> 4-bank shift/row

typedef short short8 __attribute__((ext_vector_type(8)));
typedef float f32x4 __attribute__((ext_vector_type(4)));

// ---------------- LayerNorm: one block (256 thr) per row of 1024 ----------------
__global__ __launch_bounds__(256) void ln_kernel(const float* __restrict__ x,
                                                 const float* __restrict__ g,
                                                 const float* __restrict__ bta,
                                                 float* __restrict__ out) {
    int row = blockIdx.x;
    int tid = threadIdx.x;
    const float* xr = x + (size_t)row * D_;
    int c = tid * 4;
    float4 v = *(const float4*)&xr[c];
    float s = v.x + v.y + v.z + v.w;
#pragma unroll
    for (int off = 32; off >= 1; off >>= 1) s += __shfl_xor(s, off);
    __shared__ float sm[4], sv[4];
    int wid = tid >> 6, lane = tid & 63;
    if (lane == 0) sm[wid] = s;
    __syncthreads();
    float mean = (sm[0] + sm[1] + sm[2] + sm[3]) * (1.0f / D_);
    float d0 = v.x - mean, d1 = v.y - mean, d2 = v.z - mean, d3 = v.w - mean;
    float qq = d0*d0 + d1*d1 + d2*d2 + d3*d3;
#pragma unroll
    for (int off = 32; off >= 1; off >>= 1) qq += __shfl_xor(qq, off);
    if (lane == 0) sv[wid] = qq;
    __syncthreads();
    float var = (sv[0] + sv[1] + sv[2] + sv[3]) * (1.0f / D_);
    float rstd = rsqrtf(var + 1e-5f);
    float4 gg = *(const float4*)&g[c];
    float4 bb = *(const float4*)&bta[c];
    float4 o;
    o.x = d0 * rstd * gg.x + bb.x;
    o.y = d1 * rstd * gg.y + bb.y;
    o.z = d2 * rstd * gg.z + bb.z;
    o.w = d3 * rstd * gg.w + bb.w;
    *(float4*)&(out + (size_t)row * D_)[c] = o;
}

// ---------------- Generic f32 GEMM: C = res + act(A(MxK) * W(NxK)^T + bias) ----------------
__global__ __launch_bounds__(256) void gemm_bt(const float* __restrict__ A,
                                               const float* __restrict__ W,
                                               const float* __restrict__ bias,
                                               const float* __restrict__ res,
                                               float* __restrict__ C,
                                               int M, int N, int K, int do_gelu) {
    __shared__ float As[64][17];
    __shared__ float Ws[64][17];
    int bm = blockIdx.y * 64, bn = blockIdx.x * 64;
    int tid = threadIdx.x;
    int lr = tid >> 2;
    int lk = (tid & 3) * 4;
    int ty = tid >> 4, tx = tid & 15;
    float acc[4][4] = {{0.f}};
    for (int k0 = 0; k0 < K; k0 += 16) {
        float4 av = *(const float4*)&A[(size_t)(bm + lr) * K + k0 + lk];
        float4 wv = *(const float4*)&W[(size_t)(bn + lr) * K + k0 + lk];
        As[lr][lk+0] = av.x; As[lr][lk+1] = av.y; As[lr][lk+2] = av.z; As[lr][lk+3] = av.w;
        Ws[lr][lk+0] = wv.x; Ws[lr][lk+1] = wv.y; Ws[lr][lk+2] = wv.z; Ws[lr][lk+3] = wv.w;
        __syncthreads();
#pragma unroll
        for (int kk = 0; kk < 16; ++kk) {
            float a[4], w[4];
#pragma unroll
            for (int i = 0; i < 4; ++i) a[i] = As[ty*4 + i][kk];
#pragma unroll
            for (int j = 0; j < 4; ++j) w[j] = Ws[tx*4 + j][kk];
#pragma unroll
            for (int i = 0; i < 4; ++i)
#pragma unroll
                for (int j = 0; j < 4; ++j) acc[i][j] = fmaf(a[i], w[j], acc[i][j]);
        }
        __syncthreads();
    }
#pragma unroll
    for (int i = 0; i < 4; ++i) {
        int row = bm + ty*4 + i;
#pragma unroll
        for (int j = 0; j < 4; ++j) {
            int col = bn + tx*4 + j;
            float val = acc[i][j];
            if (bias) val += bias[col];
            if (do_gelu) val = 0.5f * val * (1.0f + erff(val * 0.70710678118654752f));
            if (res) val += res[(size_t)row * N + col];
            C[(size_t)row * N + col] = val;
        }
    }
}

// ---------------- RoPE + cast q -> qb (bf16, pre-scaled by 1/8), layout [B*QH][T][HD] ----------------
__global__ __launch_bounds__(256) void rope_cast_q(const float* __restrict__ q,
                                                   const float* __restrict__ cosb,
                                                   const float* __restrict__ sinb,
                                                   __hip_bfloat16* __restrict__ qb) {
    int idx = blockIdx.x * 256 + threadIdx.x;   // total 64*2048*32
    int d2 = idx & 31;
    int t  = (idx >> 5) & (T_ - 1);
    int bh = idx >> 16;          // 0..63
    int b = bh >> 4, h = bh & 15;
    float c0 = cosb[t*HD_ + 2*d2],     s0 = sinb[t*HD_ + 2*d2];
    float c1 = cosb[t*HD_ + 2*d2 + 1], s1 = sinb[t*HD_ + 2*d2 + 1];
    const float* p = q + (size_t)(b*T_ + t) * D_ + h*HD_ + 2*d2;
    float x0 = p[0], x1 = p[1];
    float r0 = (x0*c0 - x1*s0) * 0.125f;
    float r1 = (x1*c1 + x0*s1) * 0.125f;
    __hip_bfloat16* qo = qb + ((size_t)bh * T_ + t) * HD_ + 2*d2;
    qo[0] = __float2bfloat16(r0);
    qo[1] = __float2bfloat16(r1);
}

// ---------------- RoPE+cast k -> kb [B*KVH][T][HD]; cast v -> vbt [B*KVH][HD][T] (transposed) ----------------
__global__ __launch_bounds__(256) void rope_cast_kv(const float* __restrict__ kv,
                                                    const float* __restrict__ cosb,
                                                    const float* __restrict__ sinb,
                                                    __hip_bfloat16* __restrict__ kb,
                                                    __hip_bfloat16* __restrict__ vbt) {
    int idx = blockIdx.x * 256 + threadIdx.x;   // total 16*2048*32
    int d2 = idx & 31;
    int t  = (idx >> 5) & (T_ - 1);
    int bk = idx >> 16;          // 0..15
    int b = bk >> 2, kh = bk & 3;
    float c0 = cosb[t*HD_ + 2*d2],     s0 = sinb[t*HD_ + 2*d2];
    float c1 = cosb[t*HD_ + 2*d2 + 1], s1 = sinb[t*HD_ + 2*d2 + 1];
    const float* p = kv + (size_t)(b*T_ + t) * KVW + kh*(2*HD_) + 2*d2;
    float k0 = p[0], k1 = p[1];
    float v0 = p[HD_], v1 = p[HD_ + 1];
    float r0 = k0*c0 - k1*s0;
    float r1 = k1*c1 + k0*s1;
    __hip_bfloat16* ko = kb + ((size_t)bk * T_ + t) * HD_ + 2*d2;
    ko[0] = __float2bfloat16(r0);
    ko[1] = __float2bfloat16(r1);
    vbt[((size_t)bk * HD_ + 2*d2    ) * T_ + t] = __float2bfloat16(v0);
    vbt[((size_t)bk * HD_ + 2*d2 + 1) * T_ + t] = __float2bfloat16(v1);
}

// ---------------- Flash attention, bf16 MFMA. Block: 64 q-rows of one head; 4 waves x 16 rows ----
__global__ __launch_bounds__(256) void attn_mfma(const __hip_bfloat16* __restrict__ qb,
                                                 const __hip_bfloat16* __restrict__ kb,
                                                 const __hip_bfloat16* __restrict__ vbt,
                                                 float* __restrict__ o) {
    __shared__ __hip_bfloat16 Ks[64 * LDK];   // [key][d]
    __shared__ __hip_bfloat16 Vs[64 * LDK];   // [d][key]  (transposed V)
    __shared__ __hip_bfloat16 Ps[64 * LDK];   // [qrow][key]
    int tid = threadIdx.x;
    int w = tid >> 6, lane = tid & 63;
    int l15 = lane & 15, lhi = lane >> 4;
    int bh = blockIdx.y;               // b*QH + h
    int b = bh >> 4, h = bh & 15;
    int bk = b * KVH + (h >> 2);       // GQA: kv head = h/4
    int qt0 = blockIdx.x * 64;

    // Q fragments (A-operand, rows = q rows of this wave)
    const __hip_bfloat16* qrow = qb + ((size_t)bh * T_ + qt0 + w*16 + l15) * HD_;
    short8 qf0 = *(const short8*)(qrow + lhi*8);
    short8 qf1 = *(const short8*)(qrow + 32 + lhi*8);

    f32x4 oacc[4] = {};
    float m_run[4] = {-INFINITY, -INFINITY, -INFINITY, -INFINITY};
    float l_run[4] = {0.f, 0.f, 0.f, 0.f};

    int sr = tid >> 2;            // staging row 0..63
    int sc = (tid & 3) * 16;      // staging col seg
    const __hip_bfloat16* kbase = kb  + (size_t)bk * T_ * HD_;
    const __hip_bfloat16* vbase = vbt + (size_t)bk * HD_ * T_;

    for (int s0 = 0; s0 < T_; s0 += 64) {
        *(short8*)&Ks[sr*LDK + sc]     = *(const short8*)(kbase + (size_t)(s0+sr)*HD_ + sc);
        *(short8*)&Ks[sr*LDK + sc + 8] = *(const short8*)(kbase + (size_t)(s0+sr)*HD_ + sc + 8);
        *(short8*)&Vs[sr*LDK + sc]     = *(const short8*)(vbase + (size_t)sr*T_ + s0 + sc);
        *(short8*)&Vs[sr*LDK + sc + 8] = *(const short8*)(vbase + (size_t)sr*T_ + s0 + sc + 8);
        __syncthreads();

        // S = Q K^T : per wave 16 q-rows x 64 keys, 4 col-blocks x 2 k-steps
        f32x4 accs[4];
#pragma unroll
        for (int cb = 0; cb < 4; ++cb) {
            f32x4 z = {0.f, 0.f, 0.f, 0.f};
            short8 b0 = *(const short8*)&Ks[(cb*16 + l15)*LDK + lhi*8];
            short8 b1 = *(const short8*)&Ks[(cb*16 + l15)*LDK + 32 + lhi*8];
            z = __builtin_amdgcn_mfma_f32_16x16x32_bf16(qf0, b0, z, 0, 0, 0);
            z = __builtin_amdgcn_mfma_f32_16x16x32_bf16(qf1, b1, z, 0, 0, 0);
            accs[cb] = z;
        }

        // online softmax: row r lives in reg r of the 16-lane group lhi (row = lhi*4+r)
#pragma unroll
        for (int r = 0; r < 4; ++r) {
            float mx = fmaxf(fmaxf(accs[0][r], accs[1][r]), fmaxf(accs[2][r], accs[3][r]));
#pragma unroll
            for (int off = 1; off <= 8; off <<= 1) mx = fmaxf(mx, __shfl_xor(mx, off));
            float mn = fmaxf(m_run[r], mx);
            float cr = __expf(m_run[r] - mn);
            m_run[r] = mn;
            float p0 = __expf(accs[0][r] - mn), p1 = __expf(accs[1][r] - mn);
            float p2 = __expf(accs[2][r] - mn), p3 = __expf(accs[3][r] - mn);
            float rs = p0 + p1 + p2 + p3;
#pragma unroll
            for (int off = 1; off <= 8; off <<= 1) rs += __shfl_xor(rs, off);
            l_run[r] = l_run[r] * cr + rs;
            oacc[0][r] *= cr; oacc[1][r] *= cr; oacc[2][r] *= cr; oacc[3][r] *= cr;
            int prow = (w*16 + lhi*4 + r) * LDK + l15;
            Ps[prow]      = __float2bfloat16(p0);
            Ps[prow + 16] = __float2bfloat16(p1);
            Ps[prow + 32] = __float2bfloat16(p2);
            Ps[prow + 48] = __float2bfloat16(p3);
        }
        __syncthreads();   // Ps visible (cross-lane within wave)

        // O += P V : A = P rows (own 16 q-rows), B-operand = Vt rows (d), contraction over keys
#pragma unroll
        for (int kk = 0; kk < 2; ++kk) {
            short8 af = *(const short8*)&Ps[(w*16 + l15)*LDK + kk*32 + lhi*8];
#pragma unroll
            for (int cb = 0; cb < 4; ++cb) {
                short8 bf = *(const short8*)&Vs[(cb*16 + l15)*LDK + kk*32 + lhi*8];
                oacc[cb] = __builtin_amdgcn_mfma_f32_16x16x32_bf16(af, bf, oacc[cb], 0, 0, 0);
            }
        }
        __syncthreads();   // done with Ks/Vs before restage
    }

#pragma unroll
    for (int r = 0; r < 4; ++r) {
        int t = qt0 + w*16 + lhi*4 + r;
        float inv = 1.0f / l_run[r];
        float* orow = o + (size_t)(b*T_ + t) * D_ + h*HD_ + l15;
        orow[0]  = oacc[0][r] * inv;
        orow[16] = oacc[1][r] * inv;
        orow[32] = oacc[2][r] * inv;
        orow[48] = oacc[3][r] * inv;
    }
}

extern "C" void kernel_launch(void* const* d_in, const int* in_sizes, int n_in,
                              void* d_out, int out_size, void* d_ws, size_t ws_size,
                              hipStream_t stream) {
    const float* x    = (const float*)d_in[0];
    const float* cosb = (const float*)d_in[1];
    const float* sinb = (const float*)d_in[2];
    const float* Wq   = (const float*)d_in[3];
    const float* Wkv  = (const float*)d_in[4];
    const float* Wo   = (const float*)d_in[5];
    const float* ln1g = (const float*)d_in[6];
    const float* ln1b = (const float*)d_in[7];
    const float* ln2g = (const float*)d_in[8];
    const float* ln2b = (const float*)d_in[9];
    const float* W1   = (const float*)d_in[10];
    const float* b1   = (const float*)d_in[11];
    const float* W2   = (const float*)d_in[12];
    const float* b2   = (const float*)d_in[13];
    float* out = (float*)d_out;

    float* ws = (float*)d_ws;
    const size_t M = 1024 * 1024;
    // layout (floats):
    // [0,8M)   h  (reused as h2)
    // [8M,16M) x2
    // [16M,24M) q f32  -> o (after rope_cast)  -> gbuf part
    // [24M,28M) kv f32                          -> gbuf part
    // [28M,32M) qb (bf16, 8M elems)             -> gbuf part
    // [32M,33M) kb (bf16, 2M elems)
    // [33M,34M) vbt (bf16, 2M elems)
    float* h   = ws;
    float* x2  = ws + 8*M;
    float* q   = ws + 16*M;
    float* o   = ws + 16*M;
    float* kvb = ws + 24*M;
    __hip_bfloat16* qb  = (__hip_bfloat16*)(ws + 28*M);
    __hip_bfloat16* kbb = (__hip_bfloat16*)(ws + 32*M);
    __hip_bfloat16* vbt = (__hip_bfloat16*)(ws + 33*M);
    float* h2   = h;
    float* gbuf = ws + 16*M;   // 16M floats, overlays q/o + kvb + qb (all dead by step 7)

    // 1. LN1
    ln_kernel<<<R_, 256, 0, stream>>>(x, ln1g, ln1b, h);
    // 2. q = h @ Wq^T ; kv = h @ Wkv^T   (f32)
    gemm_bt<<<dim3(D_/64,  R_/64), 256, 0, stream>>>(h, Wq,  nullptr, nullptr, q,   R_, D_,  D_, 0);
    gemm_bt<<<dim3(KVW/64, R_/64), 256, 0, stream>>>(h, Wkv, nullptr, nullptr, kvb, R_, KVW, D_, 0);
    // 3. RoPE + bf16 cast (q scaled by 1/8; v transposed)
    rope_cast_q <<<(R_*QH*32)/256,  256, 0, stream>>>(q,   cosb, sinb, qb);
    rope_cast_kv<<<(R_*KVH*32)/256, 256, 0, stream>>>(kvb, cosb, sinb, kbb, vbt);
    // 4. attention -> o (f32)
    attn_mfma<<<dim3(T_/64, B_*QH), 256, 0, stream>>>(qb, kbb, vbt, o);
    // 5. x2 = x + o @ Wo^T
    gemm_bt<<<dim3(D_/64, R_/64), 256, 0, stream>>>(o, Wo, nullptr, x, x2, R_, D_, D_, 0);
    // 6. LN2
    ln_kernel<<<R_, 256, 0, stream>>>(x2, ln2g, ln2b, h2);
    // 7. g = gelu(h2 @ W1^T + b1)
    gemm_bt<<<dim3(DFF/64, R_/64), 256, 0, stream>>>(h2, W1, b1, nullptr, gbuf, R_, DFF, D_, 1);
    // 8. out = x2 + g @ W2^T + b2
    gemm_bt<<<dim3(D_/64, R_/64), 256, 0, stream>>>(gbuf, W2, b2, x2, out, R_, D_, DFF, 0);
}

// Round 8
// 481.553 us; speedup vs baseline: 38.2084x; 5.1567x over previous
//
#include <hip/hip_runtime.h>
#include <hip/hip_bf16.h>
#include <math.h>
#include <stdint.h>

#define B_   4
#define T_   2048
#define D_   1024
#define QH   16
#define KVH  4
#define HD_  64
#define R_   (B_*T_)      // 8192 rows
#define DFF  2048
#define QKVW 1536         // fused q(1024) + kv(512) output width
#define LDK  72           // attn LDS row stride

typedef short short8 __attribute__((ext_vector_type(8)));
typedef float f32x4 __attribute__((ext_vector_type(4)));

static __device__ __forceinline__ unsigned short f2bu(float x) {
    __hip_bfloat16 h = __float2bfloat16(x);
    return *reinterpret_cast<unsigned short*>(&h);
}

__device__ __forceinline__ void gload_lds16(const void* g, void* l) {
    typedef __attribute__((address_space(1))) void gv_t;
    typedef __attribute__((address_space(3))) void lv_t;
    __builtin_amdgcn_global_load_lds((gv_t*)g, (lv_t*)l, 16, 0, 0);
}

// ---------------- f32 -> bf16 cast (weights) ----------------
__global__ __launch_bounds__(256) void castw(const float* __restrict__ src,
                                             __hip_bfloat16* __restrict__ dst, int n4) {
    int i = blockIdx.x * 256 + threadIdx.x;
    if (i >= n4) return;
    float4 v = *(const float4*)&src[i*4];
    ushort4 o = { f2bu(v.x), f2bu(v.y), f2bu(v.z), f2bu(v.w) };
    *(ushort4*)&dst[i*4] = o;
}

// ---------------- LayerNorm -> bf16 out: one block per row ----------------
__global__ __launch_bounds__(256) void ln_bf16(const float* __restrict__ x,
                                               const float* __restrict__ g,
                                               const float* __restrict__ bta,
                                               __hip_bfloat16* __restrict__ out) {
    int row = blockIdx.x;
    int tid = threadIdx.x;
    const float* xr = x + (size_t)row * D_;
    int c = tid * 4;
    float4 v = *(const float4*)&xr[c];
    float s = v.x + v.y + v.z + v.w;
#pragma unroll
    for (int off = 32; off >= 1; off >>= 1) s += __shfl_xor(s, off);
    __shared__ float sm[4], sv[4];
    int wid = tid >> 6, lane = tid & 63;
    if (lane == 0) sm[wid] = s;
    __syncthreads();
    float mean = (sm[0] + sm[1] + sm[2] + sm[3]) * (1.0f / D_);
    float d0 = v.x - mean, d1 = v.y - mean, d2 = v.z - mean, d3 = v.w - mean;
    float qq = d0*d0 + d1*d1 + d2*d2 + d3*d3;
#pragma unroll
    for (int off = 32; off >= 1; off >>= 1) qq += __shfl_xor(qq, off);
    if (lane == 0) sv[wid] = qq;
    __syncthreads();
    float var = (sv[0] + sv[1] + sv[2] + sv[3]) * (1.0f / D_);
    float rstd = rsqrtf(var + 1e-5f);
    float4 gg = *(const float4*)&g[c];
    float4 bb = *(const float4*)&bta[c];
    ushort4 o = { f2bu(d0 * rstd * gg.x + bb.x),
                  f2bu(d1 * rstd * gg.y + bb.y),
                  f2bu(d2 * rstd * gg.z + bb.z),
                  f2bu(d3 * rstd * gg.w + bb.w) };
    *(ushort4*)&(out + (size_t)row * D_)[c] = o;
}

// ---------------- bf16 MFMA GEMM: C = res + act(A(MxK) * W(NxK)^T + bias) ----------------
// m97 structure: 128x128 tile, BK=32, 256 thr (2x2 waves), 4x4 16x16x32 frags/wave.
// MODE: 0 plain f32 out; 1 +res f32; 2 +bias,gelu -> bf16; 3 +bias,+res f32
template<int MODE>
__global__ __launch_bounds__(256) void gemm_mfma(const __hip_bfloat16* __restrict__ A,
                                                 const __hip_bfloat16* __restrict__ W,
                                                 const float* __restrict__ bias,
                                                 const float* __restrict__ res,
                                                 float* __restrict__ Cf,
                                                 __hip_bfloat16* __restrict__ Cb,
                                                 int M, int N, int K) {
    __shared__ __hip_bfloat16 At[128*32];
    __shared__ __hip_bfloat16 Bt[128*32];
    int tid = threadIdx.x;
    int w = tid >> 6, lane = tid & 63;
    int l15 = lane & 15, lhi = lane >> 4;
    int bm = blockIdx.y * 128, bn = blockIdx.x * 128;
    int wr = w >> 1, wc = w & 1;
    f32x4 acc[4][4] = {};

    for (int k0 = 0; k0 < K; k0 += 32) {
#pragma unroll
        for (int iss = 0; iss < 2; ++iss) {
            int off = (iss*256 + tid) * 8;     // element offset in 128x32 tile
            int row = off >> 5, col = off & 31;
            gload_lds16(A + (size_t)(bm + row) * K + k0 + col, &At[off]);
            gload_lds16(W + (size_t)(bn + row) * K + k0 + col, &Bt[off]);
        }
        __syncthreads();
        short8 af[4], bf[4];
#pragma unroll
        for (int m = 0; m < 4; ++m) af[m] = *(const short8*)&At[(wr*64 + m*16 + l15)*32 + lhi*8];
#pragma unroll
        for (int n = 0; n < 4; ++n) bf[n] = *(const short8*)&Bt[(wc*64 + n*16 + l15)*32 + lhi*8];
#pragma unroll
        for (int m = 0; m < 4; ++m)
#pragma unroll
            for (int n = 0; n < 4; ++n)
                acc[m][n] = __builtin_amdgcn_mfma_f32_16x16x32_bf16(af[m], bf[n], acc[m][n], 0, 0, 0);
        __syncthreads();
    }

#pragma unroll
    for (int m = 0; m < 4; ++m) {
#pragma unroll
        for (int j = 0; j < 4; ++j) {
            int row = bm + wr*64 + m*16 + lhi*4 + j;
#pragma unroll
            for (int n = 0; n < 4; ++n) {
                int col = bn + wc*64 + n*16 + l15;
                float val = acc[m][n][j];
                if (MODE == 2 || MODE == 3) val += bias[col];
                if (MODE == 2) val = 0.5f * val * (1.0f + erff(val * 0.70710678118654752f));
                if (MODE == 1 || MODE == 3) val += res[(size_t)row * N + col];
                if (MODE == 2) Cb[(size_t)row * N + col] = __float2bfloat16(val);
                else           Cf[(size_t)row * N + col] = val;
            }
        }
    }
}

// ---------------- RoPE + cast q (from fused qkv f32) -> qb bf16 [B*QH][T][HD], pre-scaled 1/8 ----
__global__ __launch_bounds__(256) void rope_cast_q(const float* __restrict__ qkv,
                                                   const float* __restrict__ cosb,
                                                   const float* __restrict__ sinb,
                                                   __hip_bfloat16* __restrict__ qb) {
    int idx = blockIdx.x * 256 + threadIdx.x;   // total 64*2048*32
    int d2 = idx & 31;
    int t  = (idx >> 5) & (T_ - 1);
    int bh = idx >> 16;          // 0..63
    int b = bh >> 4, h = bh & 15;
    float c0 = cosb[t*HD_ + 2*d2],     s0 = sinb[t*HD_ + 2*d2];
    float c1 = cosb[t*HD_ + 2*d2 + 1], s1 = sinb[t*HD_ + 2*d2 + 1];
    const float* p = qkv + (size_t)(b*T_ + t) * QKVW + h*HD_ + 2*d2;
    float x0 = p[0], x1 = p[1];
    float r0 = (x0*c0 - x1*s0) * 0.125f;
    float r1 = (x1*c1 + x0*s1) * 0.125f;
    __hip_bfloat16* qo = qb + ((size_t)bh * T_ + t) * HD_ + 2*d2;
    qo[0] = __float2bfloat16(r0);
    qo[1] = __float2bfloat16(r1);
}

// ---------------- RoPE+cast k -> kb [B*KVH][T][HD]; v -> vbt [B*KVH][HD][T] ----------------
__global__ __launch_bounds__(256) void rope_cast_kv(const float* __restrict__ qkv,
                                                    const float* __restrict__ cosb,
                                                    const float* __restrict__ sinb,
                                                    __hip_bfloat16* __restrict__ kb,
                                                    __hip_bfloat16* __restrict__ vbt) {
    int idx = blockIdx.x * 256 + threadIdx.x;   // total 16*2048*32
    int d2 = idx & 31;
    int t  = (idx >> 5) & (T_ - 1);
    int bk = idx >> 16;          // 0..15
    int b = bk >> 2, kh = bk & 3;
    float c0 = cosb[t*HD_ + 2*d2],     s0 = sinb[t*HD_ + 2*d2];
    float c1 = cosb[t*HD_ + 2*d2 + 1], s1 = sinb[t*HD_ + 2*d2 + 1];
    const float* p = qkv + (size_t)(b*T_ + t) * QKVW + 1024 + kh*(2*HD_) + 2*d2;
    float k0 = p[0], k1 = p[1];
    float v0 = p[HD_], v1 = p[HD_ + 1];
    float r0 = k0*c0 - k1*s0;
    float r1 = k1*c1 + k0*s1;
    __hip_bfloat16* ko = kb + ((size_t)bk * T_ + t) * HD_ + 2*d2;
    ko[0] = __float2bfloat16(r0);
    ko[1] = __float2bfloat16(r1);
    vbt[((size_t)bk * HD_ + 2*d2    ) * T_ + t] = __float2bfloat16(v0);
    vbt[((size_t)bk * HD_ + 2*d2 + 1) * T_ + t] = __float2bfloat16(v1);
}

// ---------------- Flash attention, bf16 MFMA -> bf16 O ----------------
__global__ __launch_bounds__(256) void attn_mfma(const __hip_bfloat16* __restrict__ qb,
                                                 const __hip_bfloat16* __restrict__ kb,
                                                 const __hip_bfloat16* __restrict__ vbt,
                                                 __hip_bfloat16* __restrict__ ob) {
    __shared__ __hip_bfloat16 Ks[64 * LDK];
    __shared__ __hip_bfloat16 Vs[64 * LDK];
    __shared__ __hip_bfloat16 Ps[64 * LDK];
    int tid = threadIdx.x;
    int w = tid >> 6, lane = tid & 63;
    int l15 = lane & 15, lhi = lane >> 4;
    int bh = blockIdx.y;
    int b = bh >> 4, h = bh & 15;
    int bk = b * KVH + (h >> 2);
    int qt0 = blockIdx.x * 64;

    const __hip_bfloat16* qrow = qb + ((size_t)bh * T_ + qt0 + w*16 + l15) * HD_;
    short8 qf0 = *(const short8*)(qrow + lhi*8);
    short8 qf1 = *(const short8*)(qrow + 32 + lhi*8);

    f32x4 oacc[4] = {};
    float m_run[4] = {-INFINITY, -INFINITY, -INFINITY, -INFINITY};
    float l_run[4] = {0.f, 0.f, 0.f, 0.f};

    int sr = tid >> 2;
    int sc = (tid & 3) * 16;
    const __hip_bfloat16* kbase = kb  + (size_t)bk * T_ * HD_;
    const __hip_bfloat16* vbase = vbt + (size_t)bk * HD_ * T_;

    for (int s0 = 0; s0 < T_; s0 += 64) {
        *(short8*)&Ks[sr*LDK + sc]     = *(const short8*)(kbase + (size_t)(s0+sr)*HD_ + sc);
        *(short8*)&Ks[sr*LDK + sc + 8] = *(const short8*)(kbase + (size_t)(s0+sr)*HD_ + sc + 8);
        *(short8*)&Vs[sr*LDK + sc]     = *(const short8*)(vbase + (size_t)sr*T_ + s0 + sc);
        *(short8*)&Vs[sr*LDK + sc + 8] = *(const short8*)(vbase + (size_t)sr*T_ + s0 + sc + 8);
        __syncthreads();

        f32x4 accs[4];
#pragma unroll
        for (int cb = 0; cb < 4; ++cb) {
            f32x4 z = {0.f, 0.f, 0.f, 0.f};
            short8 b0 = *(const short8*)&Ks[(cb*16 + l15)*LDK + lhi*8];
            short8 b1 = *(const short8*)&Ks[(cb*16 + l15)*LDK + 32 + lhi*8];
            z = __builtin_amdgcn_mfma_f32_16x16x32_bf16(qf0, b0, z, 0, 0, 0);
            z = __builtin_amdgcn_mfma_f32_16x16x32_bf16(qf1, b1, z, 0, 0, 0);
            accs[cb] = z;
        }

#pragma unroll
        for (int r = 0; r < 4; ++r) {
            float mx = fmaxf(fmaxf(accs[0][r], accs[1][r]), fmaxf(accs[2][r], accs[3][r]));
#pragma unroll
            for (int off = 1; off <= 8; off <<= 1) mx = fmaxf(mx, __shfl_xor(mx, off));
            float mn = fmaxf(m_run[r], mx);
            float cr = __expf(m_run[r] - mn);
            m_run[r] = mn;
            float p0 = __expf(accs[0][r] - mn), p1 = __expf(accs[1][r] - mn);
            float p2 = __expf(accs[2][r] - mn), p3 = __expf(accs[3][r] - mn);
            float rs = p0 + p1 + p2 + p3;
#pragma unroll
            for (int off = 1; off <= 8; off <<= 1) rs += __shfl_xor(rs, off);
            l_run[r] = l_run[r] * cr + rs;
            oacc[0][r] *= cr; oacc[1][r] *= cr; oacc[2][r] *= cr; oacc[3][r] *= cr;
            int prow = (w*16 + lhi*4 + r) * LDK + l15;
            Ps[prow]      = __float2bfloat16(p0);
            Ps[prow + 16] = __float2bfloat16(p1);
            Ps[prow + 32] = __float2bfloat16(p2);
            Ps[prow + 48] = __float2bfloat16(p3);
        }
        __syncthreads();

#pragma unroll
        for (int kk = 0; kk < 2; ++kk) {
            short8 af = *(const short8*)&Ps[(w*16 + l15)*LDK + kk*32 + lhi*8];
#pragma unroll
            for (int cb = 0; cb < 4; ++cb) {
                short8 bfv = *(const short8*)&Vs[(cb*16 + l15)*LDK + kk*32 + lhi*8];
                oacc[cb] = __builtin_amdgcn_mfma_f32_16x16x32_bf16(af, bfv, oacc[cb], 0, 0, 0);
            }
        }
        __syncthreads();
    }

#pragma unroll
    for (int r = 0; r < 4; ++r) {
        int t = qt0 + w*16 + lhi*4 + r;
        float inv = 1.0f / l_run[r];
        __hip_bfloat16* orow = ob + (size_t)(b*T_ + t) * D_ + h*HD_ + l15;
        orow[0]  = __float2bfloat16(oacc[0][r] * inv);
        orow[16] = __float2bfloat16(oacc[1][r] * inv);
        orow[32] = __float2bfloat16(oacc[2][r] * inv);
        orow[48] = __float2bfloat16(oacc[3][r] * inv);
    }
}

extern "C" void kernel_launch(void* const* d_in, const int* in_sizes, int n_in,
                              void* d_out, int out_size, void* d_ws, size_t ws_size,
                              hipStream_t stream) {
    const float* x    = (const float*)d_in[0];
    const float* cosb = (const float*)d_in[1];
    const float* sinb = (const float*)d_in[2];
    const float* Wq   = (const float*)d_in[3];
    const float* Wkv  = (const float*)d_in[4];
    const float* Wo   = (const float*)d_in[5];
    const float* ln1g = (const float*)d_in[6];
    const float* ln1b = (const float*)d_in[7];
    const float* ln2g = (const float*)d_in[8];
    const float* ln2b = (const float*)d_in[9];
    const float* W1   = (const float*)d_in[10];
    const float* b1   = (const float*)d_in[11];
    const float* W2   = (const float*)d_in[12];
    const float* b2   = (const float*)d_in[13];
    float* out = (float*)d_out;

    float* ws = (float*)d_ws;
    const size_t M = 1024 * 1024;
    // layout (float units):
    // [0,4M)    hb bf16 (8M elems)  — LN1 out, later LN2 out
    // [4M,12M)  x2 f32
    // [12M,24M) qkv f32 (8192x1536) — dead after rope; overlaid by:
    //           gbuf bf16 (16M el = 8M fl) at [12M,20M); ob bf16 (8M el = 4M fl) at [20M,24M)
    // [24M,28M) qb bf16; [28M,29M) kb; [29M,30M) vbt
    // [30M,30.75M) Wqkvb; [30.75M,31.25M) Wob; [31.25M,32.25M) W1b; [32.25M,33.25M) W2b
    __hip_bfloat16* hb   = (__hip_bfloat16*)(ws);
    float*          x2   = ws + 4*M;
    float*          qkv  = ws + 12*M;
    __hip_bfloat16* gbuf = (__hip_bfloat16*)(ws + 12*M);
    __hip_bfloat16* ob   = (__hip_bfloat16*)(ws + 20*M);
    __hip_bfloat16* qb   = (__hip_bfloat16*)(ws + 24*M);
    __hip_bfloat16* kbb  = (__hip_bfloat16*)(ws + 28*M);
    __hip_bfloat16* vbt  = (__hip_bfloat16*)(ws + 29*M);
    __hip_bfloat16* Wqkvb= (__hip_bfloat16*)(ws + 30*M);
    __hip_bfloat16* Wob  = (__hip_bfloat16*)(ws + 30*M + 3*M/4);
    __hip_bfloat16* W1b  = (__hip_bfloat16*)(ws + 31*M + M/4);
    __hip_bfloat16* W2b  = (__hip_bfloat16*)(ws + 32*M + M/4);

    // 0. weight casts (bf16)
    castw<<<(1024*1024/4 + 255)/256, 256, 0, stream>>>(Wq,  Wqkvb,              1024*1024/4);
    castw<<<( 512*1024/4 + 255)/256, 256, 0, stream>>>(Wkv, Wqkvb + 1024*1024,   512*1024/4);
    castw<<<(1024*1024/4 + 255)/256, 256, 0, stream>>>(Wo,  Wob,               1024*1024/4);
    castw<<<(2048*1024/4 + 255)/256, 256, 0, stream>>>(W1,  W1b,               2048*1024/4);
    castw<<<(2048*1024/4 + 255)/256, 256, 0, stream>>>(W2,  W2b,               2048*1024/4);

    // 1. LN1 -> hb (bf16)
    ln_bf16<<<R_, 256, 0, stream>>>(x, ln1g, ln1b, hb);
    // 2. qkv = hb @ Wqkvb^T (f32 out)
    gemm_mfma<0><<<dim3(QKVW/128, R_/128), 256, 0, stream>>>(hb, Wqkvb, nullptr, nullptr, qkv, nullptr, R_, QKVW, D_);
    // 3. RoPE + bf16 cast
    rope_cast_q <<<(R_*QH*32)/256,  256, 0, stream>>>(qkv, cosb, sinb, qb);
    rope_cast_kv<<<(R_*KVH*32)/256, 256, 0, stream>>>(qkv, cosb, sinb, kbb, vbt);
    // 4. attention -> ob (bf16)
    attn_mfma<<<dim3(T_/64, B_*QH), 256, 0, stream>>>(qb, kbb, vbt, ob);
    // 5. x2 = x + ob @ Wob^T
    gemm_mfma<1><<<dim3(D_/128, R_/128), 256, 0, stream>>>(ob, Wob, nullptr, x, x2, nullptr, R_, D_, D_);
    // 6. LN2 -> hb (bf16)
    ln_bf16<<<R_, 256, 0, stream>>>(x2, ln2g, ln2b, hb);
    // 7. gbuf = gelu(hb @ W1b^T + b1) (bf16 out)
    gemm_mfma<2><<<dim3(DFF/128, R_/128), 256, 0, stream>>>(hb, W1b, b1, nullptr, nullptr, gbuf, R_, DFF, D_);
    // 8. out = x2 + gbuf @ W2b^T + b2
    gemm_mfma<3><<<dim3(D_/128, R_/128), 256, 0, stream>>>(gbuf, W2b, b2, x2, out, nullptr, R_, D_, DFF);
}

// Round 9
// 406.490 us; speedup vs baseline: 45.2640x; 1.1847x over previous
//
#include <hip/hip_runtime.h>
#include <hip/hip_bf16.h>
#include <math.h>
#include <stdint.h>

#define B_   4
#define T_   2048
#define D_   1024
#define QH   16
#define KVH  4
#define HD_  64
#define R_   (B_*T_)      // 8192 rows
#define DFF  2048
#define QKVW 1536         // fused q(1024) + kv(512) output width
#define LDK  72           // attn LDS row stride

typedef short short8 __attribute__((ext_vector_type(8)));
typedef short short4v __attribute__((ext_vector_type(4)));
typedef float f32x4 __attribute__((ext_vector_type(4)));

static __device__ __forceinline__ unsigned short f2bu(float x) {
    __hip_bfloat16 h = __float2bfloat16(x);
    return *reinterpret_cast<unsigned short*>(&h);
}

__device__ __forceinline__ void gload_lds16(const void* g, void* l) {
    typedef __attribute__((address_space(1))) void gv_t;
    typedef __attribute__((address_space(3))) void lv_t;
    __builtin_amdgcn_global_load_lds((gv_t*)g, (lv_t*)l, 16, 0, 0);
}

// ---------------- f32 -> bf16 cast (weights) ----------------
__global__ __launch_bounds__(256) void castw(const float* __restrict__ src,
                                             __hip_bfloat16* __restrict__ dst, int n4) {
    int i = blockIdx.x * 256 + threadIdx.x;
    if (i >= n4) return;
    float4 v = *(const float4*)&src[i*4];
    ushort4 o = { f2bu(v.x), f2bu(v.y), f2bu(v.z), f2bu(v.w) };
    *(ushort4*)&dst[i*4] = o;
}

// ---------------- LayerNorm -> bf16 out: one block per row ----------------
__global__ __launch_bounds__(256) void ln_bf16(const float* __restrict__ x,
                                               const float* __restrict__ g,
                                               const float* __restrict__ bta,
                                               __hip_bfloat16* __restrict__ out) {
    int row = blockIdx.x;
    int tid = threadIdx.x;
    const float* xr = x + (size_t)row * D_;
    int c = tid * 4;
    float4 v = *(const float4*)&xr[c];
    float s = v.x + v.y + v.z + v.w;
#pragma unroll
    for (int off = 32; off >= 1; off >>= 1) s += __shfl_xor(s, off);
    __shared__ float sm[4], sv[4];
    int wid = tid >> 6, lane = tid & 63;
    if (lane == 0) sm[wid] = s;
    __syncthreads();
    float mean = (sm[0] + sm[1] + sm[2] + sm[3]) * (1.0f / D_);
    float d0 = v.x - mean, d1 = v.y - mean, d2 = v.z - mean, d3 = v.w - mean;
    float qq = d0*d0 + d1*d1 + d2*d2 + d3*d3;
#pragma unroll
    for (int off = 32; off >= 1; off >>= 1) qq += __shfl_xor(qq, off);
    if (lane == 0) sv[wid] = qq;
    __syncthreads();
    float var = (sv[0] + sv[1] + sv[2] + sv[3]) * (1.0f / D_);
    float rstd = rsqrtf(var + 1e-5f);
    float4 gg = *(const float4*)&g[c];
    float4 bb = *(const float4*)&bta[c];
    ushort4 o = { f2bu(d0 * rstd * gg.x + bb.x),
                  f2bu(d1 * rstd * gg.y + bb.y),
                  f2bu(d2 * rstd * gg.z + bb.z),
                  f2bu(d3 * rstd * gg.w + bb.w) };
    *(ushort4*)&(out + (size_t)row * D_)[c] = o;
}

// ---------------- bf16 MFMA GEMM: C = res + act(A(MxK) * W(NxK)^T + bias) ----------------
// MODE: 0 plain f32 out; 1 +res f32; 2 +bias,gelu -> bf16; 3 +bias,+res f32
template<int MODE>
__global__ __launch_bounds__(256) void gemm_mfma(const __hip_bfloat16* __restrict__ A,
                                                 const __hip_bfloat16* __restrict__ W,
                                                 const float* __restrict__ bias,
                                                 const float* __restrict__ res,
                                                 float* __restrict__ Cf,
                                                 __hip_bfloat16* __restrict__ Cb,
                                                 int M, int N, int K) {
    __shared__ __hip_bfloat16 At[128*32];
    __shared__ __hip_bfloat16 Bt[128*32];
    int tid = threadIdx.x;
    int w = tid >> 6, lane = tid & 63;
    int l15 = lane & 15, lhi = lane >> 4;
    int bm = blockIdx.y * 128, bn = blockIdx.x * 128;
    int wr = w >> 1, wc = w & 1;
    f32x4 acc[4][4] = {};

    for (int k0 = 0; k0 < K; k0 += 32) {
#pragma unroll
        for (int iss = 0; iss < 2; ++iss) {
            int off = (iss*256 + tid) * 8;     // element offset in 128x32 tile
            int row = off >> 5, col = off & 31;
            gload_lds16(A + (size_t)(bm + row) * K + k0 + col, &At[off]);
            gload_lds16(W + (size_t)(bn + row) * K + k0 + col, &Bt[off]);
        }
        __syncthreads();
        short8 af[4], bf[4];
#pragma unroll
        for (int m = 0; m < 4; ++m) af[m] = *(const short8*)&At[(wr*64 + m*16 + l15)*32 + lhi*8];
#pragma unroll
        for (int n = 0; n < 4; ++n) bf[n] = *(const short8*)&Bt[(wc*64 + n*16 + l15)*32 + lhi*8];
#pragma unroll
        for (int m = 0; m < 4; ++m)
#pragma unroll
            for (int n = 0; n < 4; ++n)
                acc[m][n] = __builtin_amdgcn_mfma_f32_16x16x32_bf16(af[m], bf[n], acc[m][n], 0, 0, 0);
        __syncthreads();
    }

#pragma unroll
    for (int m = 0; m < 4; ++m) {
#pragma unroll
        for (int j = 0; j < 4; ++j) {
            int row = bm + wr*64 + m*16 + lhi*4 + j;
#pragma unroll
            for (int n = 0; n < 4; ++n) {
                int col = bn + wc*64 + n*16 + l15;
                float val = acc[m][n][j];
                if (MODE == 2 || MODE == 3) val += bias[col];
                if (MODE == 2) val = 0.5f * val * (1.0f + erff(val * 0.70710678118654752f));
                if (MODE == 1 || MODE == 3) val += res[(size_t)row * N + col];
                if (MODE == 2) Cb[(size_t)row * N + col] = __float2bfloat16(val);
                else           Cf[(size_t)row * N + col] = val;
            }
        }
    }
}

// ---------------- RoPE + cast q (from fused qkv f32) -> qb bf16 [B*QH][T][HD], pre-scaled 1/8 ----
__global__ __launch_bounds__(256) void rope_cast_q(const float* __restrict__ qkv,
                                                   const float* __restrict__ cosb,
                                                   const float* __restrict__ sinb,
                                                   __hip_bfloat16* __restrict__ qb) {
    int idx = blockIdx.x * 256 + threadIdx.x;   // total 64*2048*32
    int d2 = idx & 31;
    int t  = (idx >> 5) & (T_ - 1);
    int bh = idx >> 16;          // 0..63
    int b = bh >> 4, h = bh & 15;
    float c0 = cosb[t*HD_ + 2*d2],     s0 = sinb[t*HD_ + 2*d2];
    float c1 = cosb[t*HD_ + 2*d2 + 1], s1 = sinb[t*HD_ + 2*d2 + 1];
    const float* p = qkv + (size_t)(b*T_ + t) * QKVW + h*HD_ + 2*d2;
    float x0 = p[0], x1 = p[1];
    float r0 = (x0*c0 - x1*s0) * 0.125f;
    float r1 = (x1*c1 + x0*s1) * 0.125f;
    __hip_bfloat16* qo = qb + ((size_t)bh * T_ + t) * HD_ + 2*d2;
    qo[0] = __float2bfloat16(r0);
    qo[1] = __float2bfloat16(r1);
}

// ---------------- RoPE+cast k -> kb [B*KVH][T][HD]; v -> vbt [B*KVH][HD][T] ----------------
__global__ __launch_bounds__(256) void rope_cast_kv(const float* __restrict__ qkv,
                                                    const float* __restrict__ cosb,
                                                    const float* __restrict__ sinb,
                                                    __hip_bfloat16* __restrict__ kb,
                                                    __hip_bfloat16* __restrict__ vbt) {
    int idx = blockIdx.x * 256 + threadIdx.x;   // total 16*2048*32
    int d2 = idx & 31;
    int t  = (idx >> 5) & (T_ - 1);
    int bk = idx >> 16;          // 0..15
    int b = bk >> 2, kh = bk & 3;
    float c0 = cosb[t*HD_ + 2*d2],     s0 = sinb[t*HD_ + 2*d2];
    float c1 = cosb[t*HD_ + 2*d2 + 1], s1 = sinb[t*HD_ + 2*d2 + 1];
    const float* p = qkv + (size_t)(b*T_ + t) * QKVW + 1024 + kh*(2*HD_) + 2*d2;
    float k0 = p[0], k1 = p[1];
    float v0 = p[HD_], v1 = p[HD_ + 1];
    float r0 = k0*c0 - k1*s0;
    float r1 = k1*c1 + k0*s1;
    __hip_bfloat16* ko = kb + ((size_t)bk * T_ + t) * HD_ + 2*d2;
    ko[0] = __float2bfloat16(r0);
    ko[1] = __float2bfloat16(r1);
    vbt[((size_t)bk * HD_ + 2*d2    ) * T_ + t] = __float2bfloat16(v0);
    vbt[((size_t)bk * HD_ + 2*d2 + 1) * T_ + t] = __float2bfloat16(v1);
}

// ---------------- Flash attention, bf16 MFMA, swapped operands -> bf16 O ----------------
// Block: 64 q-rows of one head; 4 waves x 16 q-rows. KVBLK=64.
// QK^T computed as mfma(K, Q): D[key][qrow] -> lane(l15,lhi) holds, per cb,
// S[key=cb*16+lhi*4+r][qrow=l15]: all 16 scores belong to q-row l15.
// Softmax: 15 in-lane max + 2 shuffles (xor 16, 32). P stored packed (b64).
// PV computed as mfma(V^T, P): D[d][qrow] -> lane holds O^T[d=cb*16+lhi*4+r][qrow=l15].
__global__ __launch_bounds__(256) void attn_mfma(const __hip_bfloat16* __restrict__ qb,
                                                 const __hip_bfloat16* __restrict__ kb,
                                                 const __hip_bfloat16* __restrict__ vbt,
                                                 __hip_bfloat16* __restrict__ ob) {
    __shared__ __hip_bfloat16 Ks[64 * LDK];   // [key][d]
    __shared__ __hip_bfloat16 Vs[64 * LDK];   // [d][key]
    __shared__ __hip_bfloat16 Ps[64 * LDK];   // [qrow][key]
    int tid = threadIdx.x;
    int w = tid >> 6, lane = tid & 63;
    int l15 = lane & 15, lhi = lane >> 4;
    int bh = blockIdx.y;
    int b = bh >> 4, h = bh & 15;
    int bk = b * KVH + (h >> 2);
    int qt0 = blockIdx.x * 64;

    // Q fragments (B-operand now; same row-major [row][k] read as before)
    const __hip_bfloat16* qrow = qb + ((size_t)bh * T_ + qt0 + w*16 + l15) * HD_;
    short8 qf0 = *(const short8*)(qrow + lhi*8);
    short8 qf1 = *(const short8*)(qrow + 32 + lhi*8);

    f32x4 oacc[4] = {};          // O^T[d=cb*16+lhi*4+r][qrow=l15]
    float m_run = -INFINITY, l_run = 0.0f;

    int sr = tid >> 2;
    int sc = (tid & 3) * 16;
    const __hip_bfloat16* kbase = kb  + (size_t)bk * T_ * HD_;
    const __hip_bfloat16* vbase = vbt + (size_t)bk * HD_ * T_;

    for (int s0 = 0; s0 < T_; s0 += 64) {
        *(short8*)&Ks[sr*LDK + sc]     = *(const short8*)(kbase + (size_t)(s0+sr)*HD_ + sc);
        *(short8*)&Ks[sr*LDK + sc + 8] = *(const short8*)(kbase + (size_t)(s0+sr)*HD_ + sc + 8);
        *(short8*)&Vs[sr*LDK + sc]     = *(const short8*)(vbase + (size_t)sr*T_ + s0 + sc);
        *(short8*)&Vs[sr*LDK + sc + 8] = *(const short8*)(vbase + (size_t)sr*T_ + s0 + sc + 8);
        __syncthreads();

        // S^T = K Q^T: accs[cb][r] = S[key=cb*16+lhi*4+r][qrow=l15]
        f32x4 accs[4];
#pragma unroll
        for (int cb = 0; cb < 4; ++cb) {
            f32x4 z = {0.f, 0.f, 0.f, 0.f};
            short8 k0 = *(const short8*)&Ks[(cb*16 + l15)*LDK + lhi*8];
            short8 k1 = *(const short8*)&Ks[(cb*16 + l15)*LDK + 32 + lhi*8];
            z = __builtin_amdgcn_mfma_f32_16x16x32_bf16(k0, qf0, z, 0, 0, 0);
            z = __builtin_amdgcn_mfma_f32_16x16x32_bf16(k1, qf1, z, 0, 0, 0);
            accs[cb] = z;
        }

        // online softmax for q-row l15 (all 16 scores lane-local; 4 lhi groups partition keys)
        float mx = -INFINITY;
#pragma unroll
        for (int cb = 0; cb < 4; ++cb)
#pragma unroll
            for (int r = 0; r < 4; ++r) mx = fmaxf(mx, accs[cb][r]);
        mx = fmaxf(mx, __shfl_xor(mx, 16));
        mx = fmaxf(mx, __shfl_xor(mx, 32));
        float mn = fmaxf(m_run, mx);
        float cr = __expf(m_run - mn);
        m_run = mn;
        float rs = 0.0f;
#pragma unroll
        for (int cb = 0; cb < 4; ++cb) {
            f32x4 p;
#pragma unroll
            for (int r = 0; r < 4; ++r) { p[r] = __expf(accs[cb][r] - mn); rs += p[r]; }
            short4v pk = { (short)f2bu(p[0]), (short)f2bu(p[1]),
                           (short)f2bu(p[2]), (short)f2bu(p[3]) };
            *(short4v*)&Ps[l15*LDK + cb*16 + lhi*4] = pk;   // one b64 store per cb
        }
        rs += __shfl_xor(rs, 16);
        rs += __shfl_xor(rs, 32);
        l_run = l_run * cr + rs;
#pragma unroll
        for (int cb = 0; cb < 4; ++cb)
#pragma unroll
            for (int r = 0; r < 4; ++r) oacc[cb][r] *= cr;
        __syncthreads();   // Ps visible (same-wave producers, but keep it simple & safe)

        // O^T += V^T P^T : A = Vs rows (d), B = Ps rows (qrow), contraction over keys
#pragma unroll
        for (int kk = 0; kk < 2; ++kk) {
            short8 pf = *(const short8*)&Ps[l15*LDK + kk*32 + lhi*8];
#pragma unroll
            for (int cb = 0; cb < 4; ++cb) {
                short8 vf = *(const short8*)&Vs[(cb*16 + l15)*LDK + kk*32 + lhi*8];
                oacc[cb] = __builtin_amdgcn_mfma_f32_16x16x32_bf16(vf, pf, oacc[cb], 0, 0, 0);
            }
        }
        __syncthreads();   // done with Ks/Vs/Ps before restage
    }

    // write O: lane holds O^T[d=cb*16+lhi*4+r][qrow=l15] -> 4 packed 8B stores
    float inv = 1.0f / l_run;
    int t = qt0 + w*16 + l15;
    __hip_bfloat16* orow = ob + (size_t)(b*T_ + t) * D_ + h*HD_;
#pragma unroll
    for (int cb = 0; cb < 4; ++cb) {
        short4v okv = { (short)f2bu(oacc[cb][0] * inv), (short)f2bu(oacc[cb][1] * inv),
                        (short)f2bu(oacc[cb][2] * inv), (short)f2bu(oacc[cb][3] * inv) };
        *(short4v*)&orow[cb*16 + lhi*4] = okv;
    }
}

extern "C" void kernel_launch(void* const* d_in, const int* in_sizes, int n_in,
                              void* d_out, int out_size, void* d_ws, size_t ws_size,
                              hipStream_t stream) {
    const float* x    = (const float*)d_in[0];
    const float* cosb = (const float*)d_in[1];
    const float* sinb = (const float*)d_in[2];
    const float* Wq   = (const float*)d_in[3];
    const float* Wkv  = (const float*)d_in[4];
    const float* Wo   = (const float*)d_in[5];
    const float* ln1g = (const float*)d_in[6];
    const float* ln1b = (const float*)d_in[7];
    const float* ln2g = (const float*)d_in[8];
    const float* ln2b = (const float*)d_in[9];
    const float* W1   = (const float*)d_in[10];
    const float* b1   = (const float*)d_in[11];
    const float* W2   = (const float*)d_in[12];
    const float* b2   = (const float*)d_in[13];
    float* out = (float*)d_out;

    float* ws = (float*)d_ws;
    const size_t M = 1024 * 1024;
    __hip_bfloat16* hb   = (__hip_bfloat16*)(ws);
    float*          x2   = ws + 4*M;
    float*          qkv  = ws + 12*M;
    __hip_bfloat16* gbuf = (__hip_bfloat16*)(ws + 12*M);
    __hip_bfloat16* ob   = (__hip_bfloat16*)(ws + 20*M);
    __hip_bfloat16* qb   = (__hip_bfloat16*)(ws + 24*M);
    __hip_bfloat16* kbb  = (__hip_bfloat16*)(ws + 28*M);
    __hip_bfloat16* vbt  = (__hip_bfloat16*)(ws + 29*M);
    __hip_bfloat16* Wqkvb= (__hip_bfloat16*)(ws + 30*M);
    __hip_bfloat16* Wob  = (__hip_bfloat16*)(ws + 30*M + 3*M/4);
    __hip_bfloat16* W1b  = (__hip_bfloat16*)(ws + 31*M + M/4);
    __hip_bfloat16* W2b  = (__hip_bfloat16*)(ws + 32*M + M/4);

    // 0. weight casts (bf16)
    castw<<<(1024*1024/4 + 255)/256, 256, 0, stream>>>(Wq,  Wqkvb,              1024*1024/4);
    castw<<<( 512*1024/4 + 255)/256, 256, 0, stream>>>(Wkv, Wqkvb + 1024*1024,   512*1024/4);
    castw<<<(1024*1024/4 + 255)/256, 256, 0, stream>>>(Wo,  Wob,               1024*1024/4);
    castw<<<(2048*1024/4 + 255)/256, 256, 0, stream>>>(W1,  W1b,               2048*1024/4);
    castw<<<(2048*1024/4 + 255)/256, 256, 0, stream>>>(W2,  W2b,               2048*1024/4);

    // 1. LN1 -> hb (bf16)
    ln_bf16<<<R_, 256, 0, stream>>>(x, ln1g, ln1b, hb);
    // 2. qkv = hb @ Wqkvb^T (f32 out)
    gemm_mfma<0><<<dim3(QKVW/128, R_/128), 256, 0, stream>>>(hb, Wqkvb, nullptr, nullptr, qkv, nullptr, R_, QKVW, D_);
    // 3. RoPE + bf16 cast
    rope_cast_q <<<(R_*QH*32)/256,  256, 0, stream>>>(qkv, cosb, sinb, qb);
    rope_cast_kv<<<(R_*KVH*32)/256, 256, 0, stream>>>(qkv, cosb, sinb, kbb, vbt);
    // 4. attention -> ob (bf16)
    attn_mfma<<<dim3(T_/64, B_*QH), 256, 0, stream>>>(qb, kbb, vbt, ob);
    // 5. x2 = x + ob @ Wob^T
    gemm_mfma<1><<<dim3(D_/128, R_/128), 256, 0, stream>>>(ob, Wob, nullptr, x, x2, nullptr, R_, D_, D_);
    // 6. LN2 -> hb (bf16)
    ln_bf16<<<R_, 256, 0, stream>>>(x2, ln2g, ln2b, hb);
    // 7. gbuf = gelu(hb @ W1b^T + b1) (bf16 out)
    gemm_mfma<2><<<dim3(DFF/128, R_/128), 256, 0, stream>>>(hb, W1b, b1, nullptr, nullptr, gbuf, R_, DFF, D_);
    // 8. out = x2 + gbuf @ W2b^T + b2
    gemm_mfma<3><<<dim3(D_/128, R_/128), 256, 0, stream>>>(gbuf, W2b, b2, x2, out, nullptr, R_, D_, DFF);
}

// Round 10
// 393.980 us; speedup vs baseline: 46.7013x; 1.0318x over previous
//
#include <hip/hip_runtime.h>
#include <hip/hip_bf16.h>
#include <math.h>
#include <stdint.h>

#define B_   4
#define T_   2048
#define D_   1024
#define QH   16
#define KVH  4
#define HD_  64
#define R_   (B_*T_)      // 8192 rows
#define DFF  2048
#define QKVW 1536         // fused q(1024) + kv(512) output width

typedef short short8 __attribute__((ext_vector_type(8)));
typedef short short4v __attribute__((ext_vector_type(4)));
typedef float f32x4 __attribute__((ext_vector_type(4)));

static __device__ __forceinline__ unsigned short f2bu(float x) {
    __hip_bfloat16 h = __float2bfloat16(x);
    return *reinterpret_cast<unsigned short*>(&h);
}

// swizzled byte offset within a [64][64]-bf16 (128B/row) LDS tile
#define KSWZ(row, cbyte) (((row) << 7) + ((cbyte) ^ (((row) & 7) << 4)))

__device__ __forceinline__ void gload_lds16(const void* g, void* l) {
    typedef __attribute__((address_space(1))) void gv_t;
    typedef __attribute__((address_space(3))) void lv_t;
    __builtin_amdgcn_global_load_lds((gv_t*)g, (lv_t*)l, 16, 0, 0);
}

// ---------------- f32 -> bf16 cast (weights) ----------------
__global__ __launch_bounds__(256) void castw(const float* __restrict__ src,
                                             __hip_bfloat16* __restrict__ dst, int n4) {
    int i = blockIdx.x * 256 + threadIdx.x;
    if (i >= n4) return;
    float4 v = *(const float4*)&src[i*4];
    ushort4 o = { f2bu(v.x), f2bu(v.y), f2bu(v.z), f2bu(v.w) };
    *(ushort4*)&dst[i*4] = o;
}

// ---------------- LayerNorm -> bf16 out: one block per row ----------------
__global__ __launch_bounds__(256) void ln_bf16(const float* __restrict__ x,
                                               const float* __restrict__ g,
                                               const float* __restrict__ bta,
                                               __hip_bfloat16* __restrict__ out) {
    int row = blockIdx.x;
    int tid = threadIdx.x;
    const float* xr = x + (size_t)row * D_;
    int c = tid * 4;
    float4 v = *(const float4*)&xr[c];
    float s = v.x + v.y + v.z + v.w;
#pragma unroll
    for (int off = 32; off >= 1; off >>= 1) s += __shfl_xor(s, off);
    __shared__ float sm[4], sv[4];
    int wid = tid >> 6, lane = tid & 63;
    if (lane == 0) sm[wid] = s;
    __syncthreads();
    float mean = (sm[0] + sm[1] + sm[2] + sm[3]) * (1.0f / D_);
    float d0 = v.x - mean, d1 = v.y - mean, d2 = v.z - mean, d3 = v.w - mean;
    float qq = d0*d0 + d1*d1 + d2*d2 + d3*d3;
#pragma unroll
    for (int off = 32; off >= 1; off >>= 1) qq += __shfl_xor(qq, off);
    if (lane == 0) sv[wid] = qq;
    __syncthreads();
    float var = (sv[0] + sv[1] + sv[2] + sv[3]) * (1.0f / D_);
    float rstd = rsqrtf(var + 1e-5f);
    float4 gg = *(const float4*)&g[c];
    float4 bb = *(const float4*)&bta[c];
    ushort4 o = { f2bu(d0 * rstd * gg.x + bb.x),
                  f2bu(d1 * rstd * gg.y + bb.y),
                  f2bu(d2 * rstd * gg.z + bb.z),
                  f2bu(d3 * rstd * gg.w + bb.w) };
    *(ushort4*)&(out + (size_t)row * D_)[c] = o;
}

// ---------------- bf16 MFMA GEMM: C = res + act(A(MxK) * W(NxK)^T + bias) ----------------
// MODE: 0 plain f32 out; 1 +res f32; 2 +bias,gelu -> bf16; 3 +bias,+res f32
template<int MODE>
__global__ __launch_bounds__(256) void gemm_mfma(const __hip_bfloat16* __restrict__ A,
                                                 const __hip_bfloat16* __restrict__ W,
                                                 const float* __restrict__ bias,
                                                 const float* __restrict__ res,
                                                 float* __restrict__ Cf,
                                                 __hip_bfloat16* __restrict__ Cb,
                                                 int M, int N, int K) {
    __shared__ __hip_bfloat16 At[128*32];
    __shared__ __hip_bfloat16 Bt[128*32];
    int tid = threadIdx.x;
    int w = tid >> 6, lane = tid & 63;
    int l15 = lane & 15, lhi = lane >> 4;
    int bm = blockIdx.y * 128, bn = blockIdx.x * 128;
    int wr = w >> 1, wc = w & 1;
    f32x4 acc[4][4] = {};

    for (int k0 = 0; k0 < K; k0 += 32) {
#pragma unroll
        for (int iss = 0; iss < 2; ++iss) {
            int off = (iss*256 + tid) * 8;     // element offset in 128x32 tile
            int row = off >> 5, col = off & 31;
            gload_lds16(A + (size_t)(bm + row) * K + k0 + col, &At[off]);
            gload_lds16(W + (size_t)(bn + row) * K + k0 + col, &Bt[off]);
        }
        __syncthreads();
        short8 af[4], bf[4];
#pragma unroll
        for (int m = 0; m < 4; ++m) af[m] = *(const short8*)&At[(wr*64 + m*16 + l15)*32 + lhi*8];
#pragma unroll
        for (int n = 0; n < 4; ++n) bf[n] = *(const short8*)&Bt[(wc*64 + n*16 + l15)*32 + lhi*8];
#pragma unroll
        for (int m = 0; m < 4; ++m)
#pragma unroll
            for (int n = 0; n < 4; ++n)
                acc[m][n] = __builtin_amdgcn_mfma_f32_16x16x32_bf16(af[m], bf[n], acc[m][n], 0, 0, 0);
        __syncthreads();
    }

#pragma unroll
    for (int m = 0; m < 4; ++m) {
#pragma unroll
        for (int j = 0; j < 4; ++j) {
            int row = bm + wr*64 + m*16 + lhi*4 + j;
#pragma unroll
            for (int n = 0; n < 4; ++n) {
                int col = bn + wc*64 + n*16 + l15;
                float val = acc[m][n][j];
                if (MODE == 2 || MODE == 3) val += bias[col];
                if (MODE == 2) val = 0.5f * val * (1.0f + erff(val * 0.70710678118654752f));
                if (MODE == 1 || MODE == 3) val += res[(size_t)row * N + col];
                if (MODE == 2) Cb[(size_t)row * N + col] = __float2bfloat16(val);
                else           Cf[(size_t)row * N + col] = val;
            }
        }
    }
}

// ---------------- RoPE + cast q (from fused qkv f32) -> qb bf16 [B*QH][T][HD], pre-scaled 1/8 ----
__global__ __launch_bounds__(256) void rope_cast_q(const float* __restrict__ qkv,
                                                   const float* __restrict__ cosb,
                                                   const float* __restrict__ sinb,
                                                   __hip_bfloat16* __restrict__ qb) {
    int idx = blockIdx.x * 256 + threadIdx.x;   // total 64*2048*32
    int d2 = idx & 31;
    int t  = (idx >> 5) & (T_ - 1);
    int bh = idx >> 16;          // 0..63
    int b = bh >> 4, h = bh & 15;
    float c0 = cosb[t*HD_ + 2*d2],     s0 = sinb[t*HD_ + 2*d2];
    float c1 = cosb[t*HD_ + 2*d2 + 1], s1 = sinb[t*HD_ + 2*d2 + 1];
    const float* p = qkv + (size_t)(b*T_ + t) * QKVW + h*HD_ + 2*d2;
    float x0 = p[0], x1 = p[1];
    float r0 = (x0*c0 - x1*s0) * 0.125f;
    float r1 = (x1*c1 + x0*s1) * 0.125f;
    __hip_bfloat16* qo = qb + ((size_t)bh * T_ + t) * HD_ + 2*d2;
    qo[0] = __float2bfloat16(r0);
    qo[1] = __float2bfloat16(r1);
}

// ---------------- RoPE+cast k -> kb [B*KVH][T][HD]; v -> vbt [B*KVH][HD][T] ----------------
__global__ __launch_bounds__(256) void rope_cast_kv(const float* __restrict__ qkv,
                                                    const float* __restrict__ cosb,
                                                    const float* __restrict__ sinb,
                                                    __hip_bfloat16* __restrict__ kb,
                                                    __hip_bfloat16* __restrict__ vbt) {
    int idx = blockIdx.x * 256 + threadIdx.x;   // total 16*2048*32
    int d2 = idx & 31;
    int t  = (idx >> 5) & (T_ - 1);
    int bk = idx >> 16;          // 0..15
    int b = bk >> 2, kh = bk & 3;
    float c0 = cosb[t*HD_ + 2*d2],     s0 = sinb[t*HD_ + 2*d2];
    float c1 = cosb[t*HD_ + 2*d2 + 1], s1 = sinb[t*HD_ + 2*d2 + 1];
    const float* p = qkv + (size_t)(b*T_ + t) * QKVW + 1024 + kh*(2*HD_) + 2*d2;
    float k0 = p[0], k1 = p[1];
    float v0 = p[HD_], v1 = p[HD_ + 1];
    float r0 = k0*c0 - k1*s0;
    float r1 = k1*c1 + k0*s1;
    __hip_bfloat16* ko = kb + ((size_t)bk * T_ + t) * HD_ + 2*d2;
    ko[0] = __float2bfloat16(r0);
    ko[1] = __float2bfloat16(r1);
    vbt[((size_t)bk * HD_ + 2*d2    ) * T_ + t] = __float2bfloat16(v0);
    vbt[((size_t)bk * HD_ + 2*d2 + 1) * T_ + t] = __float2bfloat16(v1);
}

// ---------------- Flash attention, bf16 MFMA, swapped operands, swizzled LDS ----------------
// Block: 64 q-rows of one head; 4 waves x 16 q-rows. KVBLK=64.
// QK^T as mfma(K,Q): lane(l15,lhi) holds S[key=cb*16+lhi*4+r][qrow=l15] (all for q-row l15).
// PV as mfma(V^T,P): lane holds O^T[d=cb*16+lhi*4+r][qrow=l15].
// Ps rows are PER-WAVE (w*16+l15) — fixes the R9 cross-wave race.
// LDS tiles are [64][64] bf16 with XOR swizzle byte^=((row&7)<<4): all accesses <=2-way.
__global__ __launch_bounds__(256) void attn_mfma(const __hip_bfloat16* __restrict__ qb,
                                                 const __hip_bfloat16* __restrict__ kb,
                                                 const __hip_bfloat16* __restrict__ vbt,
                                                 __hip_bfloat16* __restrict__ ob) {
    __shared__ __hip_bfloat16 Ks[64*64];   // [key][d]   swizzled
    __shared__ __hip_bfloat16 Vs[64*64];   // [d][key]   swizzled
    __shared__ __hip_bfloat16 Ps[64*64];   // [qrow][key] swizzled, per-wave rows
    char* KsB = (char*)Ks; char* VsB = (char*)Vs; char* PsB = (char*)Ps;
    int tid = threadIdx.x;
    int w = tid >> 6, lane = tid & 63;
    int l15 = lane & 15, lhi = lane >> 4;
    int bh = blockIdx.y;
    int b = bh >> 4, h = bh & 15;
    int bk = b * KVH + (h >> 2);
    int qt0 = blockIdx.x * 64;

    const __hip_bfloat16* qrow = qb + ((size_t)bh * T_ + qt0 + w*16 + l15) * HD_;
    short8 qf0 = *(const short8*)(qrow + lhi*8);
    short8 qf1 = *(const short8*)(qrow + 32 + lhi*8);

    f32x4 oacc[4] = {};          // O^T[d=cb*16+lhi*4+r][qrow=l15]
    float m_run = -INFINITY, l_run = 0.0f;

    int sr = tid >> 2;                 // staging row 0..63
    int scB = (tid & 3) * 32;          // staging col byte {0,32,64,96}
    const __hip_bfloat16* kbase = kb  + (size_t)bk * T_ * HD_;
    const __hip_bfloat16* vbase = vbt + (size_t)bk * HD_ * T_;
    int sce = (tid & 3) * 16;          // element offset for global side

    for (int s0 = 0; s0 < T_; s0 += 64) {
        *(short8*)(KsB + KSWZ(sr, scB))      = *(const short8*)(kbase + (size_t)(s0+sr)*HD_ + sce);
        *(short8*)(KsB + KSWZ(sr, scB + 16)) = *(const short8*)(kbase + (size_t)(s0+sr)*HD_ + sce + 8);
        *(short8*)(VsB + KSWZ(sr, scB))      = *(const short8*)(vbase + (size_t)sr*T_ + s0 + sce);
        *(short8*)(VsB + KSWZ(sr, scB + 16)) = *(const short8*)(vbase + (size_t)sr*T_ + s0 + sce + 8);
        __syncthreads();

        // S^T = K Q^T
        f32x4 accs[4];
#pragma unroll
        for (int cb = 0; cb < 4; ++cb) {
            f32x4 z = {0.f, 0.f, 0.f, 0.f};
            short8 k0 = *(const short8*)(KsB + KSWZ(cb*16 + l15, lhi*16));
            short8 k1 = *(const short8*)(KsB + KSWZ(cb*16 + l15, 64 + lhi*16));
            z = __builtin_amdgcn_mfma_f32_16x16x32_bf16(k0, qf0, z, 0, 0, 0);
            z = __builtin_amdgcn_mfma_f32_16x16x32_bf16(k1, qf1, z, 0, 0, 0);
            accs[cb] = z;
        }

        // online softmax for q-row l15 (16 lane-local scores; lhi groups partition keys)
        float mx = -INFINITY;
#pragma unroll
        for (int cb = 0; cb < 4; ++cb)
#pragma unroll
            for (int r = 0; r < 4; ++r) mx = fmaxf(mx, accs[cb][r]);
        mx = fmaxf(mx, __shfl_xor(mx, 16));
        mx = fmaxf(mx, __shfl_xor(mx, 32));
        float mn = fmaxf(m_run, mx);
        float cr = __expf(m_run - mn);
        m_run = mn;
        float rs = 0.0f;
        int pr = w*16 + l15;               // per-wave P row
#pragma unroll
        for (int cb = 0; cb < 4; ++cb) {
            f32x4 p;
#pragma unroll
            for (int r = 0; r < 4; ++r) { p[r] = __expf(accs[cb][r] - mn); rs += p[r]; }
            short4v pk = { (short)f2bu(p[0]), (short)f2bu(p[1]),
                           (short)f2bu(p[2]), (short)f2bu(p[3]) };
            *(short4v*)(PsB + KSWZ(pr, cb*32 + lhi*8)) = pk;
        }
        rs += __shfl_xor(rs, 16);
        rs += __shfl_xor(rs, 32);
        l_run = l_run * cr + rs;
#pragma unroll
        for (int cb = 0; cb < 4; ++cb)
#pragma unroll
            for (int r = 0; r < 4; ++r) oacc[cb][r] *= cr;
        // no barrier needed: P write->read is same-wave (lgkmcnt-ordered)

        // O^T += V^T P^T
#pragma unroll
        for (int kk = 0; kk < 2; ++kk) {
            short8 pf = *(const short8*)(PsB + KSWZ(w*16 + l15, kk*64 + lhi*16));
#pragma unroll
            for (int cb = 0; cb < 4; ++cb) {
                short8 vf = *(const short8*)(VsB + KSWZ(cb*16 + l15, kk*64 + lhi*16));
                oacc[cb] = __builtin_amdgcn_mfma_f32_16x16x32_bf16(vf, pf, oacc[cb], 0, 0, 0);
            }
        }
        __syncthreads();   // all waves done with Ks/Vs before restage
    }

    float inv = 1.0f / l_run;
    int t = qt0 + w*16 + l15;
    __hip_bfloat16* orow = ob + (size_t)(b*T_ + t) * D_ + h*HD_;
#pragma unroll
    for (int cb = 0; cb < 4; ++cb) {
        short4v okv = { (short)f2bu(oacc[cb][0] * inv), (short)f2bu(oacc[cb][1] * inv),
                        (short)f2bu(oacc[cb][2] * inv), (short)f2bu(oacc[cb][3] * inv) };
        *(short4v*)&orow[cb*16 + lhi*4] = okv;
    }
}

extern "C" void kernel_launch(void* const* d_in, const int* in_sizes, int n_in,
                              void* d_out, int out_size, void* d_ws, size_t ws_size,
                              hipStream_t stream) {
    const float* x    = (const float*)d_in[0];
    const float* cosb = (const float*)d_in[1];
    const float* sinb = (const float*)d_in[2];
    const float* Wq   = (const float*)d_in[3];
    const float* Wkv  = (const float*)d_in[4];
    const float* Wo   = (const float*)d_in[5];
    const float* ln1g = (const float*)d_in[6];
    const float* ln1b = (const float*)d_in[7];
    const float* ln2g = (const float*)d_in[8];
    const float* ln2b = (const float*)d_in[9];
    const float* W1   = (const float*)d_in[10];
    const float* b1   = (const float*)d_in[11];
    const float* W2   = (const float*)d_in[12];
    const float* b2   = (const float*)d_in[13];
    float* out = (float*)d_out;

    float* ws = (float*)d_ws;
    const size_t M = 1024 * 1024;
    __hip_bfloat16* hb   = (__hip_bfloat16*)(ws);
    float*          x2   = ws + 4*M;
    float*          qkv  = ws + 12*M;
    __hip_bfloat16* gbuf = (__hip_bfloat16*)(ws + 12*M);
    __hip_bfloat16* ob   = (__hip_bfloat16*)(ws + 20*M);
    __hip_bfloat16* qb   = (__hip_bfloat16*)(ws + 24*M);
    __hip_bfloat16* kbb  = (__hip_bfloat16*)(ws + 28*M);
    __hip_bfloat16* vbt  = (__hip_bfloat16*)(ws + 29*M);
    __hip_bfloat16* Wqkvb= (__hip_bfloat16*)(ws + 30*M);
    __hip_bfloat16* Wob  = (__hip_bfloat16*)(ws + 30*M + 3*M/4);
    __hip_bfloat16* W1b  = (__hip_bfloat16*)(ws + 31*M + M/4);
    __hip_bfloat16* W2b  = (__hip_bfloat16*)(ws + 32*M + M/4);

    // 0. weight casts (bf16)
    castw<<<(1024*1024/4 + 255)/256, 256, 0, stream>>>(Wq,  Wqkvb,              1024*1024/4);
    castw<<<( 512*1024/4 + 255)/256, 256, 0, stream>>>(Wkv, Wqkvb + 1024*1024,   512*1024/4);
    castw<<<(1024*1024/4 + 255)/256, 256, 0, stream>>>(Wo,  Wob,               1024*1024/4);
    castw<<<(2048*1024/4 + 255)/256, 256, 0, stream>>>(W1,  W1b,               2048*1024/4);
    castw<<<(2048*1024/4 + 255)/256, 256, 0, stream>>>(W2,  W2b,               2048*1024/4);

    // 1. LN1 -> hb (bf16)
    ln_bf16<<<R_, 256, 0, stream>>>(x, ln1g, ln1b, hb);
    // 2. qkv = hb @ Wqkvb^T (f32 out)
    gemm_mfma<0><<<dim3(QKVW/128, R_/128), 256, 0, stream>>>(hb, Wqkvb, nullptr, nullptr, qkv, nullptr, R_, QKVW, D_);
    // 3. RoPE + bf16 cast
    rope_cast_q <<<(R_*QH*32)/256,  256, 0, stream>>>(qkv, cosb, sinb, qb);
    rope_cast_kv<<<(R_*KVH*32)/256, 256, 0, stream>>>(qkv, cosb, sinb, kbb, vbt);
    // 4. attention -> ob (bf16)
    attn_mfma<<<dim3(T_/64, B_*QH), 256, 0, stream>>>(qb, kbb, vbt, ob);
    // 5. x2 = x + ob @ Wob^T
    gemm_mfma<1><<<dim3(D_/128, R_/128), 256, 0, stream>>>(ob, Wob, nullptr, x, x2, nullptr, R_, D_, D_);
    // 6. LN2 -> hb (bf16)
    ln_bf16<<<R_, 256, 0, stream>>>(x2, ln2g, ln2b, hb);
    // 7. gbuf = gelu(hb @ W1b^T + b1) (bf16 out)
    gemm_mfma<2><<<dim3(DFF/128, R_/128), 256, 0, stream>>>(hb, W1b, b1, nullptr, nullptr, gbuf, R_, DFF, D_);
    // 8. out = x2 + gbuf @ W2b^T + b2
    gemm_mfma<3><<<dim3(D_/128, R_/128), 256, 0, stream>>>(gbuf, W2b, b2, x2, out, nullptr, R_, D_, DFF);
}